// Round 5
// baseline (313.910 us; speedup 1.0000x reference)
//
#include <hip/hip_runtime.h>
#include <hip/hip_bf16.h>

typedef unsigned short u16;
typedef unsigned int   u32;
typedef __attribute__((ext_vector_type(8))) short bf16x8;
typedef __attribute__((ext_vector_type(4))) float f32x4;

__device__ __forceinline__ u16 f2bf(float f) {
  u32 u = __float_as_uint(f);
  u32 r = u + 0x7fffu + ((u >> 16) & 1u);
  return (u16)(r >> 16);
}
__device__ __forceinline__ float bflo(u32 u) { return __uint_as_float(u << 16); }
__device__ __forceinline__ float bfhi(u32 u) { return __uint_as_float(u & 0xffff0000u); }
// (hi16(b)<<16)|hi16(a) in one v_perm (truncate-to-bf16)
__device__ __forceinline__ u32 packhi(float a, float b) {
  return __builtin_amdgcn_perm(__float_as_uint(b), __float_as_uint(a), 0x07060302u);
}
// XOR-swizzled LDS index (u16 units): row r (0..63), 32-bit word wo (0..31).
// Row stride 32 words; swizzle = wo ^ ((r&7)*4). <=2-way banks for all our
// b64-write / b128-read / word-linear patterns (2-way is free, m136).
__device__ __forceinline__ int pidx(int r, int wo) {
  return (r * 32 + (wo ^ ((r & 7) << 2))) * 2;
}

// ---------------------------------------------------------------------------
// Kernel 1: avgpool 2x2 + Q/K/V 1x1-conv projections via MFMA.
// grid 1024 x 256 (4 waves). side = blockIdx&1 (0: rgb->Q, 1: freq->K,V).
// Q,K stored [b][n][64] bf16; V stored [b][64][n] bf16.
// Q pre-scaled by hid^-0.5 * log2(e) (exp2 fold for k_attn).
// ---------------------------------------------------------------------------
__global__ __launch_bounds__(256, 4) void k_qkv(
    const float* __restrict__ rgb, const float* __restrict__ freq,
    const float* __restrict__ wq, const float* __restrict__ bq,
    const float* __restrict__ wk, const float* __restrict__ bk,
    const float* __restrict__ wv, const float* __restrict__ bv,
    u16* __restrict__ Qo, u16* __restrict__ Ko, u16* __restrict__ Vo)
{
  __shared__ __align__(16) u16 sm[3 * 4608];
  u16* X  = sm;             // [64][72] pooled input tokens (pad-72 kept here)
  u16* W0 = sm + 4608;      // [64][72] wq or wk
  u16* W1 = sm + 9216;      // [64][72] wv (side 1 only)

  const int t    = threadIdx.x;
  const int side = blockIdx.x & 1;
  const int seg  = blockIdx.x >> 1;       // 0..511
  const int idx0 = seg * 64;              // global token base (b*4096+n)
  const int bb   = idx0 >> 12;
  const int n0   = idx0 & 4095;
  const int h    = n0 >> 6;               // pooled row (uniform per block)
  const float* src = side ? freq : rgb;

  // ---- stage pooled X: 64 tokens (one pooled row) x 64 ch ----
  const size_t sbase = (size_t)bb * 64 * 16384 + (size_t)(2 * h) * 128;
  for (int i = 0; i < 2; ++i) {
    int cell = i * 256 + t;               // 0..511
    int tok  = cell & 63;                 // lane-consecutive -> coalesced
    int grp  = cell >> 6;                 // channel granule 0..7
    const float* p0 = src + sbase + 2 * tok + (size_t)(grp * 8) * 16384;
    u32 pk[4];
#pragma unroll
    for (int cc = 0; cc < 8; cc += 2) {
      const float* pa = p0 + (size_t)cc * 16384;
      float2 a0 = *(const float2*)pa;
      float2 a1 = *(const float2*)(pa + 128);
      float v0 = 0.25f * ((a0.x + a0.y) + (a1.x + a1.y));
      const float* pb = pa + 16384;
      float2 b0 = *(const float2*)pb;
      float2 b1 = *(const float2*)(pb + 128);
      float v1 = 0.25f * ((b0.x + b0.y) + (b1.x + b1.y));
      pk[cc >> 1] = (u32)f2bf(v0) | ((u32)f2bf(v1) << 16);
    }
    uint4 q4; q4.x = pk[0]; q4.y = pk[1]; q4.z = pk[2]; q4.w = pk[3];
    *(uint4*)&X[tok * 72 + grp * 8] = q4;
  }
  // ---- stage weights, float4-coalesced ----
  {
    const int o = t >> 2, c0 = (t & 3) << 4;
    const float4* p4 = (const float4*)((side ? wk : wq) + o * 64 + c0);
    float4 f0 = p4[0], f1 = p4[1], f2 = p4[2], f3 = p4[3];
    uint4 qa, qb;
    qa.x = (u32)f2bf(f0.x) | ((u32)f2bf(f0.y) << 16);
    qa.y = (u32)f2bf(f0.z) | ((u32)f2bf(f0.w) << 16);
    qa.z = (u32)f2bf(f1.x) | ((u32)f2bf(f1.y) << 16);
    qa.w = (u32)f2bf(f1.z) | ((u32)f2bf(f1.w) << 16);
    qb.x = (u32)f2bf(f2.x) | ((u32)f2bf(f2.y) << 16);
    qb.y = (u32)f2bf(f2.z) | ((u32)f2bf(f2.w) << 16);
    qb.z = (u32)f2bf(f3.x) | ((u32)f2bf(f3.y) << 16);
    qb.w = (u32)f2bf(f3.z) | ((u32)f2bf(f3.w) << 16);
    *(uint4*)&W0[o * 72 + c0] = qa;
    *(uint4*)&W0[o * 72 + c0 + 8] = qb;
    if (side) {
      const float4* v4 = (const float4*)(wv + o * 64 + c0);
      float4 g0 = v4[0], g1 = v4[1], g2 = v4[2], g3 = v4[3];
      qa.x = (u32)f2bf(g0.x) | ((u32)f2bf(g0.y) << 16);
      qa.y = (u32)f2bf(g0.z) | ((u32)f2bf(g0.w) << 16);
      qa.z = (u32)f2bf(g1.x) | ((u32)f2bf(g1.y) << 16);
      qa.w = (u32)f2bf(g1.z) | ((u32)f2bf(g1.w) << 16);
      qb.x = (u32)f2bf(g2.x) | ((u32)f2bf(g2.y) << 16);
      qb.y = (u32)f2bf(g2.z) | ((u32)f2bf(g2.w) << 16);
      qb.z = (u32)f2bf(g3.x) | ((u32)f2bf(g3.y) << 16);
      qb.w = (u32)f2bf(g3.z) | ((u32)f2bf(g3.w) << 16);
      *(uint4*)&W1[o * 72 + c0] = qa;
      *(uint4*)&W1[o * 72 + c0 + 8] = qb;
    }
  }
  __syncthreads();

  const int lane = t & 63, w = t >> 6;
  const int l15 = lane & 15, qd = lane >> 4;
  const int tb = w * 16;                  // wave's 16 tokens

  bf16x8 af0 = *(const bf16x8*)&X[(tb + l15) * 72 + qd * 8];
  bf16x8 af1 = *(const bf16x8*)&X[(tb + l15) * 72 + 32 + qd * 8];

  // ---- Q (side 0) / K (side 1): A = X (rows tok), B = W0 (cols o) ----
  f32x4 acc[4];
#pragma unroll
  for (int nt = 0; nt < 4; ++nt) {
    bf16x8 b0 = *(const bf16x8*)&W0[(nt * 16 + l15) * 72 + qd * 8];
    bf16x8 b1 = *(const bf16x8*)&W0[(nt * 16 + l15) * 72 + 32 + qd * 8];
    f32x4 a = {0.f, 0.f, 0.f, 0.f};
    a = __builtin_amdgcn_mfma_f32_16x16x32_bf16(af0, b0, a, 0, 0, 0);
    a = __builtin_amdgcn_mfma_f32_16x16x32_bf16(af1, b1, a, 0, 0, 0);
    acc[nt] = a;
  }
  {
    const float* bias0 = side ? bk : bq;
    const float sc = side ? 1.f : 0.18033688f;   // 0.125 * log2(e)
    u16* dst0 = side ? Ko : Qo;
#pragma unroll
    for (int nt = 0; nt < 4; ++nt) {
      float bia = bias0[nt * 16 + l15];
#pragma unroll
      for (int e = 0; e < 4; ++e) {
        int tok = idx0 + tb + qd * 4 + e;     // D row = token
        dst0[(size_t)tok * 64 + nt * 16 + l15] = f2bf((acc[nt][e] + bia) * sc);
      }
    }
  }

  if (side) {
    // ---- V: A = Wv (rows c), B = X (cols tok) -> D = V^T directly ----
    f32x4 accv[4];
#pragma unroll
    for (int ct = 0; ct < 4; ++ct) {
      bf16x8 a0 = *(const bf16x8*)&W1[(ct * 16 + l15) * 72 + qd * 8];
      bf16x8 a1 = *(const bf16x8*)&W1[(ct * 16 + l15) * 72 + 32 + qd * 8];
      f32x4 a = {0.f, 0.f, 0.f, 0.f};
      a = __builtin_amdgcn_mfma_f32_16x16x32_bf16(a0, af0, a, 0, 0, 0);
      a = __builtin_amdgcn_mfma_f32_16x16x32_bf16(a1, af1, a, 0, 0, 0);
      accv[ct] = a;
    }
#pragma unroll
    for (int ct = 0; ct < 4; ++ct) {
#pragma unroll
      for (int e = 0; e < 4; ++e) {
        int c = ct * 16 + qd * 4 + e;          // D row = V channel
        float v = accv[ct][e] + bv[c];
        Vo[((size_t)(bb * 64 + c)) * 4096 + n0 + tb + l15] = f2bf(v);
      }
    }
  }
}

// ---------------------------------------------------------------------------
// Kernel 2: attention + fused output-conv/BN epilogue.
// grid (8 b, 64 qtile) x 512 threads = 8 independent waves (no K-loop sync).
// Wave w: key-split w (keys w*512..+512, 8 tiles of 64), all 64 block-q.
// 16 waves/CU (4/SIMD). K,V frags direct from global (L2-resident per XCD).
// P / partial-Z in XOR-swizzled per-wave LDS regions (64q x 64, 8 KB).
// No-max softmax via exp2 (scale folded into Q); partials add across waves.
// Epilogue: combine+normalize (in-place), then Y = BNaffine(Wo.Z) via MFMA
// with register-held Wo fragments; store Ya[b][n][64] bf16 (conv/BN commute
// with the bilinear resize; LeakyReLU applied post-interp in k_out).
// ---------------------------------------------------------------------------
__global__ __launch_bounds__(512, 4) void k_attn(
    const u16* __restrict__ Qg, const u16* __restrict__ Kg,
    const u16* __restrict__ Vg,
    const float* __restrict__ wo, const float* __restrict__ bo,
    const float* __restrict__ gam, const float* __restrict__ bet,
    const float* __restrict__ mean, const float* __restrict__ var,
    u16* __restrict__ Ya)
{
  __shared__ __align__(16) u16 Pb[8 * 4096];   // 8 regions x 8KB, swizzled
  __shared__ float lb[8 * 64];                 // per-wave denominators

  const int b  = blockIdx.x;                   // batch -> XCD affinity
  const int q0 = blockIdx.y * 64;
  const int t  = threadIdx.x;
  const int lane = t & 63, w = t >> 6;
  const int l15 = lane & 15, qd = lane >> 4;
  u16* P = Pb + w * 4096;

  // ---- Wo B-fragments for the epilogue, kept in registers ----
  bf16x8 wf0, wf1;
  {
    const float* wop = wo + (((w & 3) * 16 + l15) * 64);
    float4 a0 = *(const float4*)(wop + qd * 8);
    float4 a1 = *(const float4*)(wop + qd * 8 + 4);
    float4 c0 = *(const float4*)(wop + 32 + qd * 8);
    float4 c1 = *(const float4*)(wop + 32 + qd * 8 + 4);
    union { u32 u[4]; bf16x8 v; } cv;
    cv.u[0] = (u32)f2bf(a0.x) | ((u32)f2bf(a0.y) << 16);
    cv.u[1] = (u32)f2bf(a0.z) | ((u32)f2bf(a0.w) << 16);
    cv.u[2] = (u32)f2bf(a1.x) | ((u32)f2bf(a1.y) << 16);
    cv.u[3] = (u32)f2bf(a1.z) | ((u32)f2bf(a1.w) << 16);
    wf0 = cv.v;
    cv.u[0] = (u32)f2bf(c0.x) | ((u32)f2bf(c0.y) << 16);
    cv.u[1] = (u32)f2bf(c0.z) | ((u32)f2bf(c0.w) << 16);
    cv.u[2] = (u32)f2bf(c1.x) | ((u32)f2bf(c1.y) << 16);
    cv.u[3] = (u32)f2bf(c1.z) | ((u32)f2bf(c1.w) << 16);
    wf1 = cv.v;
  }

  // ---- Q fragments (B-operand, scale+log2e pre-folded) ----
  bf16x8 qf[4][2];
#pragma unroll
  for (int qt = 0; qt < 4; ++qt) {
    const u16* p = Qg + ((size_t)(b * 4096 + q0 + qt * 16 + l15)) * 64 + qd * 8;
    qf[qt][0] = *(const bf16x8*)p;
    qf[qt][1] = *(const bf16x8*)(p + 32);
  }

  f32x4 zacc[4][4];                            // [ct][qt]
#pragma unroll
  for (int i = 0; i < 4; ++i)
#pragma unroll
    for (int j = 0; j < 4; ++j) {
      f32x4 z = {0.f, 0.f, 0.f, 0.f};
      zacc[i][j] = z;
    }
  float lacc[4] = {0.f, 0.f, 0.f, 0.f};

#pragma unroll 1
  for (int tile = 0; tile < 8; ++tile) {
    const int n0 = w * 512 + tile * 64;

    // ---- K frags (A-operand: rows = keys) ----
    bf16x8 kf[4][2];
#pragma unroll
    for (int mt = 0; mt < 4; ++mt) {
      const u16* p = Kg + ((size_t)(b * 4096 + n0 + mt * 16 + l15)) * 64 + qd * 8;
      kf[mt][0] = *(const bf16x8*)p;
      kf[mt][1] = *(const bf16x8*)(p + 32);
    }
    // ---- S^T = K.Q^T, exp2, pack P[q][key] ----
#pragma unroll
    for (int qt = 0; qt < 4; ++qt) {
#pragma unroll
      for (int mt = 0; mt < 4; ++mt) {
        f32x4 a = {0.f, 0.f, 0.f, 0.f};
        a = __builtin_amdgcn_mfma_f32_16x16x32_bf16(kf[mt][0], qf[qt][0], a, 0, 0, 0);
        a = __builtin_amdgcn_mfma_f32_16x16x32_bf16(kf[mt][1], qf[qt][1], a, 0, 0, 0);
        float p0 = exp2f(a[0]);
        float p1 = exp2f(a[1]);
        float p2 = exp2f(a[2]);
        float p3 = exp2f(a[3]);
        lacc[qt] += (p0 + p1) + (p2 + p3);
        uint2 pw;
        pw.x = packhi(p0, p1);
        pw.y = packhi(p2, p3);
        *(uint2*)&P[pidx(qt * 16 + l15, mt * 8 + qd * 2)] = pw;
      }
    }
    // ---- V frags (loaded after S/exp so kf regs are dead) ----
    bf16x8 vf[4][2];
#pragma unroll
    for (int ct = 0; ct < 4; ++ct) {
      const u16* p = Vg + ((size_t)(b * 64 + ct * 16 + l15)) * 4096 + n0 + qd * 8;
      vf[ct][0] = *(const bf16x8*)p;
      vf[ct][1] = *(const bf16x8*)(p + 32);
    }
    // ---- Z^T += V^T . P^T ----
#pragma unroll
    for (int qt = 0; qt < 4; ++qt) {
      bf16x8 pf0 = *(const bf16x8*)&P[pidx(qt * 16 + l15, qd * 4)];
      bf16x8 pf1 = *(const bf16x8*)&P[pidx(qt * 16 + l15, 16 + qd * 4)];
#pragma unroll
      for (int ct = 0; ct < 4; ++ct) {
        zacc[ct][qt] = __builtin_amdgcn_mfma_f32_16x16x32_bf16(vf[ct][0], pf0, zacc[ct][qt], 0, 0, 0);
        zacc[ct][qt] = __builtin_amdgcn_mfma_f32_16x16x32_bf16(vf[ct][1], pf1, zacc[ct][qt], 0, 0, 0);
      }
    }
  }

  // ---- per-wave epilogue: denominators + unnormalized partial Z [q][c] ----
#pragma unroll
  for (int qt = 0; qt < 4; ++qt) {
    float l = lacc[qt];
    l += __shfl_xor(l, 16);
    l += __shfl_xor(l, 32);
    if (qd == 0) lb[w * 64 + qt * 16 + l15] = l;
  }
#pragma unroll
  for (int qt = 0; qt < 4; ++qt)
#pragma unroll
    for (int ct = 0; ct < 4; ++ct) {
      uint2 pw;
      pw.x = packhi(zacc[ct][qt][0], zacc[ct][qt][1]);
      pw.y = packhi(zacc[ct][qt][2], zacc[ct][qt][3]);
      *(uint2*)&P[pidx(qt * 16 + l15, ct * 8 + qd * 2)] = pw;
    }
  __syncthreads();

  // ---- combine 8 key-splits + normalize, in place (cell-exclusive) ----
  {
    const u32* Pw = (const u32*)Pb;            // region stride 2048 words
    u32* Zw = (u32*)Pb;
#pragma unroll
    for (int i = 0; i < 4; ++i) {
      int cell = i * 512 + t;                  // 0..2047 = [64 q][32 words]
      int q = cell >> 5, cu = cell & 31;
      int off = q * 32 + (cu ^ ((q & 7) << 2));
      float s0 = 0.f, s1 = 0.f, ds = 0.f;
#pragma unroll
      for (int ww = 0; ww < 8; ++ww) {
        u32 v = Pw[ww * 2048 + off];
        s0 += bflo(v);
        s1 += bfhi(v);
        ds += lb[ww * 64 + q];
      }
      float inv = 1.f / ds;
      Zw[(q >> 4) * 2048 + off] = packhi(s0 * inv, s1 * inv);
    }
  }
  __syncthreads();

  // ---- Y = affine(Wo . Z): wave w -> q-tiles {2(w>>2),+1}, o-tile w&3 ----
  {
    const int nt = w & 3;
#pragma unroll
    for (int k = 0; k < 2; ++k) {
      const int qt = (w >> 2) * 2 + k;
      const int r = qt * 16 + l15;
      const u16* Zr = Pb + qt * 4096;          // region qt holds rows qt*16..
      bf16x8 af0 = *(const bf16x8*)&Zr[pidx(r, qd * 4)];
      bf16x8 af1 = *(const bf16x8*)&Zr[pidx(r, 16 + qd * 4)];
      f32x4 y = {0.f, 0.f, 0.f, 0.f};
      y = __builtin_amdgcn_mfma_f32_16x16x32_bf16(af0, wf0, y, 0, 0, 0);
      y = __builtin_amdgcn_mfma_f32_16x16x32_bf16(af1, wf1, y, 0, 0, 0);
      const int o = nt * 16 + l15;
      float A = gam[o] * __frsqrt_rn(var[o] + 1e-5f);
      float B = (bo[o] - mean[o]) * A + bet[o];
#pragma unroll
      for (int e = 0; e < 4; ++e) {
        float v = y[e] * A + B;
        size_t tok = (size_t)(b * 4096 + q0 + qt * 16 + qd * 4 + e);
        Ya[tok * 64 + o] = (u16)(__float_as_uint(v) >> 16);
      }
    }
  }
}

// ---------------------------------------------------------------------------
// Kernel 3: bilinear 2x upsample of Ya + LeakyReLU + residual.
// grid 2048 x 256: thread = one (b,i,j) pixel x 16 channels (cq quarter).
// Ya channel-innermost -> corners are contiguous 32 B bf16 runs.
// ---------------------------------------------------------------------------
__global__ __launch_bounds__(256, 8) void k_out(
    const u16* __restrict__ Ya, const float* __restrict__ rgb,
    float* __restrict__ out)
{
  const int cq = blockIdx.x >> 9;                       // channel quarter 0..3
  const int px = (blockIdx.x & 511) * 256 + threadIdx.x; // 0..131071
  const int j = px & 127;
  const int i = (px >> 7) & 127;
  const int b = px >> 14;

  float ys = fmaxf((i + 0.5f) * 0.5f - 0.5f, 0.f);
  int   y0 = (int)ys;
  float wy = ys - (float)y0;
  int   y1 = min(y0 + 1, 63);
  float xs = fmaxf((j + 0.5f) * 0.5f - 0.5f, 0.f);
  int   x0 = (int)xs;
  float wx = xs - (float)x0;
  int   x1 = min(x0 + 1, 63);
  float w00 = (1.f - wy) * (1.f - wx), w01 = (1.f - wy) * wx;
  float w10 = wy * (1.f - wx),         w11 = wy * wx;

  const u16* yb = Ya + (size_t)b * 262144 + cq * 16;
  const int b00 = (y0 * 64 + x0) * 64, b01 = (y0 * 64 + x1) * 64;
  const int b10 = (y1 * 64 + x0) * 64, b11 = (y1 * 64 + x1) * 64;

#pragma unroll
  for (int ch = 0; ch < 2; ++ch) {
    uint4 a00 = *(const uint4*)&yb[b00 + ch * 8];
    uint4 a01 = *(const uint4*)&yb[b01 + ch * 8];
    uint4 a10 = *(const uint4*)&yb[b10 + ch * 8];
    uint4 a11 = *(const uint4*)&yb[b11 + ch * 8];
    const u32* u00 = (const u32*)&a00;
    const u32* u01 = (const u32*)&a01;
    const u32* u10 = (const u32*)&a10;
    const u32* u11 = (const u32*)&a11;
#pragma unroll
    for (int e = 0; e < 8; ++e) {
      const int wd = e >> 1;
      float c00 = (e & 1) ? bfhi(u00[wd]) : bflo(u00[wd]);
      float c01 = (e & 1) ? bfhi(u01[wd]) : bflo(u01[wd]);
      float c10 = (e & 1) ? bfhi(u10[wd]) : bflo(u10[wd]);
      float c11 = (e & 1) ? bfhi(u11[wd]) : bflo(u11[wd]);
      float v = w00 * c00 + w01 * c01 + w10 * c10 + w11 * c11;
      v = (v >= 0.f) ? v : 0.2f * v;
      const int o = cq * 16 + ch * 8 + e;
      const size_t oi = ((size_t)((b * 64 + o) * 128 + i)) * 128 + j;
      out[oi] = rgb[oi] + v;
    }
  }
}

// ---------------------------------------------------------------------------
extern "C" void kernel_launch(void* const* d_in, const int* in_sizes, int n_in,
                              void* d_out, int out_size, void* d_ws, size_t ws_size,
                              hipStream_t stream) {
  (void)in_sizes; (void)n_in; (void)out_size; (void)ws_size;
  const float* rgb  = (const float*)d_in[0];
  const float* freq = (const float*)d_in[1];
  const float* wq   = (const float*)d_in[2];
  const float* bq   = (const float*)d_in[3];
  const float* wk   = (const float*)d_in[4];
  const float* bk   = (const float*)d_in[5];
  const float* wv   = (const float*)d_in[6];
  const float* bv   = (const float*)d_in[7];
  const float* wo   = (const float*)d_in[8];
  const float* bo   = (const float*)d_in[9];
  const float* gam  = (const float*)d_in[10];
  const float* bet  = (const float*)d_in[11];
  const float* mean = (const float*)d_in[12];
  const float* var  = (const float*)d_in[13];

  char* ws = (char*)d_ws;
  u16* Qw = (u16*)(ws);               // 8*4096*64 bf16 = 4 MiB
  u16* Kw = (u16*)(ws + 4194304);     // 4 MiB
  u16* Vw = (u16*)(ws + 8388608);     // 4 MiB (transposed [b][c][n])
  u16* Yw = (u16*)(ws + 12582912);    // 4 MiB  Ya[b][n][64] bf16

  k_qkv<<<dim3(1024), dim3(256), 0, stream>>>(rgb, freq, wq, bq, wk, bk, wv, bv,
                                              Qw, Kw, Vw);
  k_attn<<<dim3(8, 64), dim3(512), 0, stream>>>(Qw, Kw, Vw, wo, bo, gam, bet,
                                                mean, var, Yw);
  k_out<<<dim3(2048), dim3(256), 0, stream>>>(Yw, rgb, (float*)d_out);
}